// Round 6
// baseline (309.808 us; speedup 1.0000x reference)
//
#include <hip/hip_runtime.h>

// MEASUREMENT ROUND. lif_kernel is the correct output (round-2 structure,
// 81 us control). Two probe kernels write ONLY into d_ws (scratch) to
// isolate the 2.48 TB/s limiter:
//   probe_strided: exact same address stream as lif, no recurrence.
//   probe_linear:  same bytes, classic grid-stride contiguous copy (m13).
// Readout is the per-dispatch rocprof rows, not the aggregate dur_us.

constexpr int T_STEPS = 64;

typedef float f32x4 __attribute__((ext_vector_type(4)));

__global__ __launch_bounds__(256) void lif_kernel(const f32x4* __restrict__ x,
                                                  f32x4* __restrict__ out,
                                                  int cols4) {
    const int idx = blockIdx.x * blockDim.x + threadIdx.x;
    if (idx >= cols4) return;

    const f32x4* xp = x + idx;
    f32x4* op = out + idx;

    f32x4 v = {0.f, 0.f, 0.f, 0.f};

#pragma unroll 8
    for (int t = 0; t < T_STEPS; ++t) {
        const f32x4 xt = xp[t * cols4];
        const f32x4 h = 0.5f * (v + xt);
        f32x4 s;
        s.x = (h.x >= 1.0f) ? 1.0f : 0.0f;
        s.y = (h.y >= 1.0f) ? 1.0f : 0.0f;
        s.z = (h.z >= 1.0f) ? 1.0f : 0.0f;
        s.w = (h.w >= 1.0f) ? 1.0f : 0.0f;
        v.x = (h.x >= 1.0f) ? 0.0f : h.x;
        v.y = (h.y >= 1.0f) ? 0.0f : h.y;
        v.z = (h.z >= 1.0f) ? 0.0f : h.z;
        v.w = (h.w >= 1.0f) ? 0.0f : h.w;
        __builtin_nontemporal_store(s, &op[t * cols4]);
    }
}

// Same grid, same addresses, no recurrence: is the address pattern the limiter?
__global__ __launch_bounds__(256) void probe_strided(const f32x4* __restrict__ x,
                                                     f32x4* __restrict__ ws,
                                                     int cols4, int cap4) {
    const int idx = blockIdx.x * blockDim.x + threadIdx.x;
    if (idx >= cols4) return;

#pragma unroll 8
    for (int t = 0; t < T_STEPS; ++t) {
        const f32x4 v = x[t * cols4 + idx];
        const int o = t * cols4 + idx;
        if (o < cap4) __builtin_nontemporal_store(v, &ws[o]);
    }
}

// Same bytes, canonical grid-stride copy (m13 pattern, 6.3 TB/s reference).
__global__ __launch_bounds__(256) void probe_linear(const f32x4* __restrict__ x,
                                                    f32x4* __restrict__ ws,
                                                    int n4) {
    const int stride = gridDim.x * blockDim.x;
    for (int i = blockIdx.x * blockDim.x + threadIdx.x; i < n4; i += stride)
        __builtin_nontemporal_store(x[i], &ws[i]);
}

extern "C" void kernel_launch(void* const* d_in, const int* in_sizes, int n_in,
                              void* d_out, int out_size, void* d_ws, size_t ws_size,
                              hipStream_t stream) {
    const float* x = (const float*)d_in[0];
    float* out = (float*)d_out;

    const int total = in_sizes[0];            // T * B * N
    const int cols = total / T_STEPS;         // B * N = 524288
    const int cols4 = cols / 4;               // 131072 f32x4 columns
    const int total4 = total / 4;             // 8388608 f32x4 elements

    const int cap4 = (int)((ws_size / 16) < (size_t)total4 ? (ws_size / 16)
                                                           : (size_t)total4);

    const int block = 256;

    // 1) Real kernel -> d_out (correctness).
    lif_kernel<<<(cols4 + block - 1) / block, block, 0, stream>>>(
        (const f32x4*)x, (f32x4*)out, cols4);

    // 2) Probes -> d_ws only.
    probe_strided<<<(cols4 + block - 1) / block, block, 0, stream>>>(
        (const f32x4*)x, (f32x4*)d_ws, cols4, cap4);
    probe_linear<<<2048, block, 0, stream>>>(
        (const f32x4*)x, (f32x4*)d_ws, cap4);
}

// Round 7
// 227.706 us; speedup vs baseline: 1.3606x; 1.3606x over previous
//
#include <hip/hip_runtime.h>
#include <stdint.h>

// LIF recurrence, T=64. x: [T, B*N] f32, out: [T, B*N] f32.
// h=(v+x)/2; s=(h>=1); v=s?0:h.
//
// Round-6 diagnosis: compiler caps in-flight loads at ~4KB/wave (VGPR sink),
// => ~16KB/CU => 3.2 TB/s latency-bound. Fix: global_load_lds (no dest VGPR,
// cannot be sunk), wave-private double-buffered LDS chunks, counted vmcnt
// waits so stores never gate loads. No __syncthreads anywhere.
//
// vmcnt derivation (per wave, 8 gll + 8 stores per chunk, in-order retire):
//   chunk c needs L(c) done. Ops newer than L(c): S(c-1) x8 + L(c+1) x8.
//   c=0: only L1 newer -> vmcnt(8). c=1..6: vmcnt(16). c=7: only S6 newer -> vmcnt(8).

constexpr int T_STEPS = 64;
constexpr int CHUNK = 8;                  // t-rows per chunk
constexpr int NCHUNK = T_STEPS / CHUNK;   // 8
constexpr int WAVES = 4;                  // block = 256 threads

typedef float f32x4 __attribute__((ext_vector_type(4)));
typedef __attribute__((address_space(3))) uint8_t lds_u8;
typedef __attribute__((address_space(1))) const uint8_t glb_u8;

__global__ __launch_bounds__(256) void lif_kernel(const f32x4* __restrict__ x,
                                                  f32x4* __restrict__ out,
                                                  int cols4) {
    // [wave][buf][row][lane] = 4*2*8*64*16 B = 64 KB -> 2 blocks/CU
    __shared__ f32x4 lds[WAVES][2][CHUNK][64];

    const int tid = threadIdx.x;
    const int w = tid >> 6;
    const int lane = tid & 63;
    const int col4 = blockIdx.x * 256 + tid;

    const f32x4* xp = x + col4;
    f32x4* op = out + col4;

    auto issue_chunk = [&](int c, int p) {
#pragma unroll
        for (int r = 0; r < CHUNK; ++r) {
            const f32x4* g = xp + (c * CHUNK + r) * cols4;
            __builtin_amdgcn_global_load_lds((glb_u8*)g, (lds_u8*)&lds[w][p][r][0],
                                             16, 0, 0);
        }
        __builtin_amdgcn_sched_barrier(0);
    };

    issue_chunk(0, 0);
    issue_chunk(1, 1);

    f32x4 v = {0.f, 0.f, 0.f, 0.f};

#pragma unroll
    for (int c = 0; c < NCHUNK; ++c) {
        const int p = c & 1;
        if (c == 0 || c == NCHUNK - 1)
            asm volatile("s_waitcnt vmcnt(8)" ::: "memory");
        else
            asm volatile("s_waitcnt vmcnt(16)" ::: "memory");

#pragma unroll
        for (int r = 0; r < CHUNK; ++r) {
            const f32x4 xt = lds[w][p][r][lane];
            const f32x4 h = 0.5f * (v + xt);
            f32x4 s;
            s.x = (h.x >= 1.0f) ? 1.0f : 0.0f;
            s.y = (h.y >= 1.0f) ? 1.0f : 0.0f;
            s.z = (h.z >= 1.0f) ? 1.0f : 0.0f;
            s.w = (h.w >= 1.0f) ? 1.0f : 0.0f;
            v.x = (h.x >= 1.0f) ? 0.0f : h.x;
            v.y = (h.y >= 1.0f) ? 0.0f : h.y;
            v.z = (h.z >= 1.0f) ? 0.0f : h.z;
            v.w = (h.w >= 1.0f) ? 0.0f : h.w;
            __builtin_nontemporal_store(s, op + (c * CHUNK + r) * cols4);
        }
        __builtin_amdgcn_sched_barrier(0);

        if (c + 2 < NCHUNK) issue_chunk(c + 2, p);
    }
}

extern "C" void kernel_launch(void* const* d_in, const int* in_sizes, int n_in,
                              void* d_out, int out_size, void* d_ws, size_t ws_size,
                              hipStream_t stream) {
    const float* x = (const float*)d_in[0];
    float* out = (float*)d_out;

    const int total = in_sizes[0];            // T * B * N
    const int cols = total / T_STEPS;         // B * N = 524288
    const int cols4 = cols / 4;               // 131072 f32x4 columns

    const int block = 256;
    const int grid = (cols4 + block - 1) / block;  // 512 = 2 blocks/CU
    lif_kernel<<<grid, block, 0, stream>>>((const f32x4*)x, (f32x4*)out, cols4);
}